// Round 1
// baseline (409.522 us; speedup 1.0000x reference)
//
#include <hip/hip_runtime.h>
#include <math.h>

#define OBS_DIM 115
#define N_AGENTS 11
#define ROW_F (N_AGENTS * OBS_DIM)      // 1265 floats per gs row
#define WAVES_PER_BLOCK 4
#define ROWS_PER_WAVE 4
#define ROWS_PER_BLOCK (WAVES_PER_BLOCK * ROWS_PER_WAVE)   // 16
#define SLICE_F 388                     // per-row LDS stride (384 used + 4 pad, 388%32=4 de-conflicts groups)
#define WAVE_F (ROWS_PER_WAVE * SLICE_F) // 1552 floats per wave

// Packed per-row LDS layout (384 words used):
//   [0,242)   pos candidates: a*22 + j   <- gs col a*115 + j        (j<22)
//   [242,363) id block:       a*11 + j   <- gs col a*115 + 97 + j   (j<11)
//   [363,366) ball/team: gs cols 88, 89, 95
//   [366,377) q[r*11 + a]
//   [377,384) dummy (gs col 0, keeps all 64 lanes issuing uniformly)

typedef const __attribute__((address_space(1))) unsigned int gu32;
typedef __attribute__((address_space(3))) unsigned int lu32;

__global__ __launch_bounds__(256) void qmix_kernel(
    const float* __restrict__ q,    // [B, 11]
    const float* __restrict__ gs,   // [B, 1265]
    float* __restrict__ out,        // [B]
    int B)
{
    __shared__ float lds[WAVES_PER_BLOCK * WAVE_F];   // 24832 B

    const int tid  = threadIdx.x;
    const int wv   = tid >> 6;          // wave in block
    const int lane = tid & 63;
    const int rbase = blockIdx.x * ROWS_PER_BLOCK + wv * ROWS_PER_WAVE;

    // ---- per-lane column offsets for the 6 staging passes (shared by all 4 rows) ----
    int off[6], isq[6];
    #pragma unroll
    for (int p6 = 0; p6 < 6; ++p6) {
        const int mm = p6 * 64 + lane;
        int o = 0, iq = 0;
        if (mm < 242)      { const int a = mm / 22; o = a * OBS_DIM + (mm - a * 22); }
        else if (mm < 363) { const int t = mm - 242; const int a = t / 11;
                             o = a * OBS_DIM + 97 + (t - a * 11); }
        else if (mm == 363) o = 88;
        else if (mm == 364) o = 89;
        else if (mm == 365) o = 95;
        else if (mm < 377) { o = mm - 366; iq = 1; }
        else               o = 0;        // dummy, lands in pad words [377,384)
        off[p6] = o; isq[p6] = iq;
    }

    // ---- staging: 24 async global->LDS passes, all independent (deep MLP) ----
    #pragma unroll
    for (int p = 0; p < ROWS_PER_WAVE * 6; ++p) {
        const int rl = p / 6;            // compile-time
        const int p6 = p % 6;            // compile-time
        int rr = rbase + rl;
        if (rr >= B) rr = B - 1;         // clamp; grid divides exactly for B=65536
        const float* gbase = isq[p6] ? (q + (size_t)rr * N_AGENTS)
                                     : (gs + (size_t)rr * ROW_F);
        const float* src = gbase + off[p6];
        // LDS dest is wave-uniform base; HW places lane i at base + 4*i (linear layout matches)
        __builtin_amdgcn_global_load_lds(
            (gu32*)src,
            (lu32*)&lds[wv * WAVE_F + rl * SLICE_F + p6 * 64],
            4, 0, 0);
    }

    __syncthreads();   // drains vmcnt(0): all staged data visible in LDS

    // ---- compute: group g of this wave handles row rbase+g, 16 lanes/row ----
    const int g  = lane >> 4;
    const int s  = lane & 15;
    const int rr = rbase + g;
    const float* S = &lds[wv * WAVE_F + g * SLICE_F];

    const float bx = S[363], by = S[364], team = S[365];
    const float g0  = bx - 1.0f;
    const float bgd = sqrtf(g0 * g0 + by * by);
    const bool valid = (team != 0.0f) && (bgd > 0.19f) && (bgd < 0.99f);

    float dist = INFINITY;      // inactive lanes lose argmin
    float comb = -INFINITY;     // inactive lanes contribute exp()=0
    float qv = 0.0f, gd = 0.0f;

    if (s < N_AGENTS) {
        // argmax over ID block (first-max tie-break: strict >)
        const float* idb = S + 242 + s * 11;
        float best = idb[0]; int bi = 0;
        #pragma unroll
        for (int j = 1; j < 11; ++j) {
            float v = idb[j];
            if (v > best) { best = v; bi = j; }
        }
        const float px = S[s * 22 + 2 * bi];
        const float py = S[s * 22 + 2 * bi + 1];
        const float dx = px - bx, dy = py - by;
        dist = sqrtf(dx * dx + dy * dy);
        const float gx = px - 1.0f;
        gd = sqrtf(gx * gx + py * py);
        qv = S[366 + s];
    }

    // group argmin over dist (first-min tie-break)
    int idx = s;
    float d = dist;
    #pragma unroll
    for (int o = 8; o >= 1; o >>= 1) {
        float d2 = __shfl_xor(d, o, 16);
        int   i2 = __shfl_xor(idx, o, 16);
        if (d2 < d || (d2 == d && i2 < idx)) { d = d2; idx = i2; }
    }

    if (s < N_AGENTS)
        comb = valid ? ((s == idx) ? 5.0f : 0.0f)
                     : 1.0f / (gd + 1e-6f);

    // group max of comb
    float m = comb;
    #pragma unroll
    for (int o = 8; o >= 1; o >>= 1)
        m = fmaxf(m, __shfl_xor(m, o, 16));

    // softmax denom + weighted q sum
    float wgt = expf(comb - m);   // 0 for inactive lanes
    float wq  = wgt * qv;
    #pragma unroll
    for (int o = 8; o >= 1; o >>= 1) {
        wgt += __shfl_xor(wgt, o, 16);
        wq  += __shfl_xor(wq,  o, 16);
    }

    if (s == 0 && rr < B)
        out[rr] = wq * (float)N_AGENTS / wgt;
}

extern "C" void kernel_launch(void* const* d_in, const int* in_sizes, int n_in,
                              void* d_out, int out_size, void* d_ws, size_t ws_size,
                              hipStream_t stream) {
    const float* q  = (const float*)d_in[0];   // agents_q  [128,512,11]
    const float* gs = (const float*)d_in[1];   // global_state [128,512,1265]
    float* out = (float*)d_out;                // [128,512,1] f32

    int B = in_sizes[0] / N_AGENTS;            // 65536
    int grid = (B + ROWS_PER_BLOCK - 1) / ROWS_PER_BLOCK;  // 4096
    qmix_kernel<<<grid, 256, 0, stream>>>(q, gs, out, B);
}